// Round 2
// baseline (339.481 us; speedup 1.0000x reference)
//
#include <hip/hip_runtime.h>
#include <math.h>

#define Bn 4
#define Qn 300
#define WL 8
#define Hh 64
#define Ww 64
#define Dd 256
#define Mm 4

// ---------------- helpers ----------------
__device__ __forceinline__ float wave_reduce(float v) {
#pragma unroll
    for (int off = 32; off > 0; off >>= 1) v += __shfl_down(v, off, 64);
    return v;
}

__device__ __forceinline__ float lo16(unsigned u) { return __uint_as_float(u << 16); }
__device__ __forceinline__ float hi16(unsigned u) { return __uint_as_float(u & 0xffff0000u); }

__device__ __forceinline__ unsigned bfp(float a, float b) {
    unsigned ua = __float_as_uint(a); ua = (ua + 0x7fffu + ((ua >> 16) & 1u)) >> 16;
    unsigned ub = __float_as_uint(b); ub = (ub + 0x7fffu + ((ub >> 16) & 1u)) >> 16;
    return ua | (ub << 16);
}

__device__ __forceinline__ void unpack8(uint4 wv, float* w) {
    w[0] = lo16(wv.x); w[1] = hi16(wv.x); w[2] = lo16(wv.y); w[3] = hi16(wv.y);
    w[4] = lo16(wv.z); w[5] = hi16(wv.z); w[6] = lo16(wv.w); w[7] = hi16(wv.w);
}

__device__ __forceinline__ float dot8(float4 ha, float4 hb, const float* w) {
    return ha.x * w[0] + ha.y * w[1] + ha.z * w[2] + ha.w * w[3]
         + hb.x * w[4] + hb.y * w[5] + hb.z * w[6] + hb.w * w[7];
}

// ---------------- kernel 1: pack (blocks 0..575) + fused params+gather (576..1775) ----------------
// params phase computes LN1/PE/rel/point-params into LDS records, gather phase consumes
// them directly. LDS overlay: Prec+part live inside WcT's storage (dead after dot phase)
// -> 56KB -> ~45KB -> 3 blocks/CU for latency hiding in the gather.
__global__ void __launch_bounds__(512, 6) k_front(const float* __restrict__ wp,
                                                  const float* __restrict__ wf1,
                                                  const float* __restrict__ wf2,
                                                  unsigned* __restrict__ pk,
                                                  const float* __restrict__ q,
                                                  const float* __restrict__ g1,
                                                  const float* __restrict__ b1,
                                                  const float* __restrict__ w_ref,
                                                  const float* __restrict__ b_ref,
                                                  const float* __restrict__ dsec,
                                                  const float* __restrict__ w_rel,
                                                  const float* __restrict__ b_rel,
                                                  const float* __restrict__ w_delta,
                                                  const float* __restrict__ b_delta,
                                                  const float* __restrict__ w_alpha,
                                                  const float* __restrict__ b_alpha,
                                                  const unsigned char* __restrict__ mask,
                                                  const float* __restrict__ feats,
                                                  float* __restrict__ agg) {
    int bid = blockIdx.x, t = threadIdx.x;

    if (bid < 576) {
        // ---------------- weight packing path (576*512 = 294912 elems) ----------------
        int i = bid * 512 + t;
        if (i < 32768) {                     // pkP: K=256 (g<32), N=256
            int p = i & 3, c = (i >> 2) & 255, g = i >> 10;
            pk[i] = bfp(wp[(g * 8 + 2 * p) * 256 + c], wp[(g * 8 + 2 * p + 1) * 256 + c]);
        } else if (i < 163840) {             // pkF1: K=256 (g<32), N=1024
            int i2 = i - 32768;
            int p = i2 & 3, c = (i2 >> 2) & 1023, g = i2 >> 12;
            pk[i] = bfp(wf1[(g * 8 + 2 * p) * 1024 + c], wf1[(g * 8 + 2 * p + 1) * 1024 + c]);
        } else {                             // pkF2: K=1024 (g<128), N=256
            int i3 = i - 163840;
            int p = i3 & 3, c = (i3 >> 2) & 255, g = i3 >> 10;
            pk[i] = bfp(wf2[(g * 8 + 2 * p) * 256 + c], wf2[(g * 8 + 2 * p + 1) * 256 + c]);
        }
        return;
    }

    __shared__ float sqn[256];
    __shared__ float pe[8][64];
    __shared__ float rel[8][260];     // +4 pad: 16B-aligned float4 rows
    __shared__ __align__(16) float WcT[16 * 516];   // WcT[jj][k], row stride 516
    __shared__ float dres[2][8][16];
    __shared__ float res[8][16];
    __shared__ float red[16];
    __shared__ float sref[2];
    // ---- overlay: WcT is dead after the 16-dot phase; reuse its storage ----
    float (*part)[256] = (float (*)[256])WcT;        // 8*256 floats = 8KB at offset 0
    unsigned* Prec = (unsigned*)(WcT + 2048);        // 32*16 uints = 2KB at offset 8KB

    int bq = bid - 576;
    int ch = t & 255;
    bool lo = t < 256;
    int lane = t & 63, wv = t >> 6;

    // ---- early independent loads: w_rel column in registers (both halves) ----
    float wr[64];
#pragma unroll
    for (int k = 0; k < 64; k++) wr[k] = w_rel[k * Dd + ch];

    // ---- stage combined delta/alpha weights into LDS (transposed), 512 threads ----
    for (int u = t; u < 512 * 16; u += 512) {
        int k = u >> 4, jj = u & 15;
        float w = (jj < 12) ? w_delta[k * 12 + jj] : w_alpha[k * 4 + (jj - 12)];
        WcT[jj * 516 + k] = w;
    }

    // ---- LN1 (channels on threads 0..255) ----
    float x = lo ? q[bq * Dd + ch] : 0.f;
    float sm = wave_reduce(x);
    if (lane == 0) red[wv] = sm;
    __syncthreads();
    float m = (red[0] + red[1] + red[2] + red[3] + red[4] + red[5] + red[6] + red[7]) * (1.f / Dd);
    __syncthreads();
    float dx = lo ? (x - m) : 0.f;
    float sv = wave_reduce(dx * dx);
    if (lane == 0) red[wv] = sv;
    __syncthreads();
    float v = (red[0] + red[1] + red[2] + red[3] + red[4] + red[5] + red[6] + red[7]) * (1.f / Dd);
    __syncthreads();
    float y = 0.f;
    if (lo) { y = dx * rsqrtf(v + 1e-5f) * g1[ch] + b1[ch]; sqn[ch] = y; }

    // ---- sinusoidal PE for all 8 windows ----
    if (lo) {
        int wl = t >> 5, i2 = t & 31;
        float f = expf(-logf(10000.f) * (float)i2 * (1.f / 32.f));
        float a = dsec[bq * WL + wl] * f;
        pe[wl][i2] = sinf(a);
        pe[wl][i2 + 32] = cosf(a);
    }

    // ---- ref = sigmoid(qn @ w_ref + b_ref), both columns in one barrier ----
    float c0 = lo ? y * w_ref[2 * ch] : 0.f;
    float c1 = lo ? y * w_ref[2 * ch + 1] : 0.f;
    c0 = wave_reduce(c0); c1 = wave_reduce(c1);
    if (lane == 0) { red[wv] = c0; red[8 + wv] = c1; }
    __syncthreads();                 // also publishes pe
    if (t == 0) {
        float s0 = red[0] + red[1] + red[2] + red[3] + red[4] + red[5] + red[6] + red[7] + b_ref[0];
        float s1 = red[8] + red[9] + red[10] + red[11] + red[12] + red[13] + red[14] + red[15] + b_ref[1];
        sref[0] = 1.f / (1.f + expf(-s0));
        sref[1] = 1.f / (1.f + expf(-s1));
    }

    // ---- rel_feat: half-block per 4 windows (pe via float4 broadcast reads) ----
    {
        float brl = b_rel[ch];
        int wh = t >> 8;
#pragma unroll
        for (int w2 = 0; w2 < 4; w2++) {
            int wl = wh * 4 + w2;
            const float4* p4 = (const float4*)&pe[wl][0];
            float r = brl;
#pragma unroll
            for (int k4 = 0; k4 < 16; k4++) {
                float4 p = p4[k4];
                r += p.x * wr[4 * k4] + p.y * wr[4 * k4 + 1]
                   + p.z * wr[4 * k4 + 2] + p.w * wr[4 * k4 + 3];
            }
            rel[wl][ch] = r;
        }
    }
    __syncthreads();                 // publishes rel, WcT, sqn

    // ---- 16 dot products per window, K split in halves over 256 threads ----
    if (t < 256) {
        int h = t >> 7, idx = t & 127, wl = idx >> 4, jj = idx & 15;
        const float4* wrow = (const float4*)&WcT[jj * 516 + h * 256];
        const float4* arow = h ? (const float4*)&rel[wl][0] : (const float4*)sqn;
        float s = 0.f;
#pragma unroll 8
        for (int k4 = 0; k4 < 64; k4++) {
            float4 a = arow[k4], w = wrow[k4];
            s += a.x * w.x + a.y * w.y + a.z * w.z + a.w * w.w;
        }
        dres[h][wl][jj] = s;
    }
    __syncthreads();                 // WcT dead from here on
    if (t < 128) {
        int wl = t >> 4, jj = t & 15;
        res[wl][jj] = dres[0][wl][jj] + dres[1][wl][jj]
                    + ((jj < 12) ? b_delta[jj] : b_alpha[jj - 12]);
    }
    __syncthreads();

    // ---- per-point records into LDS (Prec overlays WcT storage) ----
    if (t < 32) {
        int wl = t >> 2, mm = t & 3;
        float l0 = res[wl][12], l1 = res[wl][13], l2 = res[wl][14], l3 = res[wl][15];
        float mx = fmaxf(fmaxf(l0, l1), fmaxf(l2, l3));
        float inv = 1.f / (expf(l0 - mx) + expf(l1 - mx) + expf(l2 - mx) + expf(l3 - mx));
        // -lam_sp*|dsec| shift is constant across M -> drops out of softmax
        float wgt = expf(res[wl][12 + mm] - mx) * inv;

        float cx = fminf(fmaxf(sref[0] + tanhf(res[wl][mm * 3 + 0]), 0.f), 1.f);
        float cy = fminf(fmaxf(sref[1] + tanhf(res[wl][mm * 3 + 1]), 0.f), 1.f);
        float tgt = (float)wl + tanhf(res[wl][mm * 3 + 2]);
        float t0f = fminf(fmaxf(floorf(tgt), 0.f), (float)(WL - 1));
        float t1f = fminf(t0f + 1.f, (float)(WL - 1));
        float alpha = tgt - t0f;
        float px = cx * (float)Ww - 0.5f, py = cy * (float)Hh - 0.5f;
        float fx = floorf(px), fy = floorf(py);
        float wx = px - fx, wy = py - fy;
        int X0 = (int)fminf(fmaxf(fx, 0.f), (float)(Ww - 1));
        int X1 = (int)fminf(fmaxf(fx + 1.f, 0.f), (float)(Ww - 1));
        int Y0 = (int)fminf(fmaxf(fy, 0.f), (float)(Hh - 1));
        int Y1 = (int)fminf(fmaxf(fy + 1.f, 0.f), (float)(Hh - 1));
        int T0 = (int)t0f, T1 = (int)t1f;

        float w00 = (1.f - wy) * (1.f - wx), w01 = (1.f - wy) * wx;
        float w10 = wy * (1.f - wx), w11 = wy * wx;
        float wt0 = wgt * (1.f - alpha), wt1 = wgt * alpha;

        int b = bq / Qn;
        int base0 = (b * WL + T0) * Hh;
        int base1 = (b * WL + T1) * Hh;
        int i00 = (base0 + Y0) * Ww + X0, i01 = (base0 + Y0) * Ww + X1;
        int i10 = (base0 + Y1) * Ww + X0, i11 = (base0 + Y1) * Ww + X1;
        int j00 = (base1 + Y0) * Ww + X0, j01 = (base1 + Y0) * Ww + X1;
        int j10 = (base1 + Y1) * Ww + X0, j11 = (base1 + Y1) * Ww + X1;

        unsigned* rec = &Prec[t * 16];
        rec[0] = __float_as_uint(wt0 * w00 * (mask[i00] ? 0.f : 1.f));
        rec[1] = __float_as_uint(wt0 * w01 * (mask[i01] ? 0.f : 1.f));
        rec[2] = __float_as_uint(wt0 * w10 * (mask[i10] ? 0.f : 1.f));
        rec[3] = __float_as_uint(wt0 * w11 * (mask[i11] ? 0.f : 1.f));
        rec[4] = __float_as_uint(wt1 * w00 * (mask[j00] ? 0.f : 1.f));
        rec[5] = __float_as_uint(wt1 * w01 * (mask[j01] ? 0.f : 1.f));
        rec[6] = __float_as_uint(wt1 * w10 * (mask[j10] ? 0.f : 1.f));
        rec[7] = __float_as_uint(wt1 * w11 * (mask[j11] ? 0.f : 1.f));
        rec[8] = i00; rec[9] = i01; rec[10] = i10; rec[11] = i11;
        rec[12] = j00; rec[13] = j01; rec[14] = j10; rec[15] = j11;
    }
    __syncthreads();

    // ---- gather + weighted aggregation (wave j owns points 4j..4j+3) ----
    {
        const float4* f4 = (const float4*)feats;
        int j = t >> 6;
        float4 acc = {0.f, 0.f, 0.f, 0.f};
#pragma unroll
        for (int p = 0; p < 4; p++) {
            const unsigned* rec = &Prec[(j * 4 + p) * 16];
#pragma unroll
            for (int cn = 0; cn < 8; cn++) {
                float w = __uint_as_float(rec[cn]);
                size_t idx = rec[8 + cn];
                float4 vv = f4[idx * 64 + lane];
                acc.x += w * vv.x; acc.y += w * vv.y; acc.z += w * vv.z; acc.w += w * vv.w;
            }
        }
        ((float4*)&part[j][0])[lane] = acc;
    }
    __syncthreads();
    if (t < 256) {
        agg[(size_t)bq * Dd + t] = part[0][t] + part[1][t] + part[2][t] + part[3][t]
                                 + part[4][t] + part[5][t] + part[6][t] + part[7][t];
    }
}

// ---------------- kernel 2: proj + residual + LN2 + FFN (+residual) ----------------
// 256 blocks x 1024 threads, 1 block/CU. Each GEMM phase: thread owns 2 columns x a
// K-slice; activation LDS broadcasts amortize over both columns (720 -> 360 b128/thread).
template<int R>
__device__ __forceinline__ void out_body(int row0,
        const float* __restrict__ q, const float* __restrict__ agg,
        const unsigned* __restrict__ pkP, const float* __restrict__ b_proj,
        const float* __restrict__ g2, const float* __restrict__ b2,
        const unsigned* __restrict__ pkF1, const float* __restrict__ b_ffn1,
        const unsigned* __restrict__ pkF2, const float* __restrict__ b_ffn2,
        float* __restrict__ out,
        float* sA, float* sO, float* sH, float* sF, float* sX, float* sRed) {
    int t = threadIdx.x;
    int j8 = t >> 7, c7 = t & 127;

    for (int u = t; u < 256 * R; u += 1024) {
        int r = u >> 8, cc = u & 255;
        sA[r * 256 + cc] = agg[(size_t)(row0 + r) * Dd + cc];
    }
    __syncthreads();

    // ---- proj: K-eighth j8 (4 groups), cols {c7, c7+128} ----
    {
        float a0[R], a1[R];
#pragma unroll
        for (int r = 0; r < R; r++) { a0[r] = 0.f; a1[r] = 0.f; }
#pragma unroll
        for (int gg = 0; gg < 4; gg++) {
            int g = j8 * 4 + gg;
            uint4 wv0 = *(const uint4*)&pkP[((unsigned)(g * 256 + c7)) * 4];
            uint4 wv1 = *(const uint4*)&pkP[((unsigned)(g * 256 + c7 + 128)) * 4];
            float w0[8], w1[8]; unpack8(wv0, w0); unpack8(wv1, w1);
#pragma unroll
            for (int r = 0; r < R; r++) {
                float4 ha = ((const float4*)&sA[r * 256])[g * 2];
                float4 hb = ((const float4*)&sA[r * 256])[g * 2 + 1];
                a0[r] += dot8(ha, hb, w0); a1[r] += dot8(ha, hb, w1);
            }
        }
#pragma unroll
        for (int r = 0; r < R; r++) {
            sX[(j8 * R + r) * 256 + c7] = a0[r];
            sX[(j8 * R + r) * 256 + c7 + 128] = a1[r];
        }
    }
    __syncthreads();

    // ---- combine + residual ----
    for (int u = t; u < 256 * R; u += 1024) {
        int r = u >> 8, cc = u & 255;
        float o = q[(size_t)(row0 + r) * Dd + cc] + b_proj[cc];
#pragma unroll
        for (int jj = 0; jj < 8; jj++) o += sX[(jj * R + r) * 256 + cc];
        sO[r * 256 + cc] = o;
    }
    __syncthreads();

    // ---- LN2: wave r reduces row r ----
    {
        int wv = t >> 6, l = t & 63;
        if (wv < R) {
            float4 vv = ((const float4*)&sO[wv * 256])[l];
            float s = vv.x + vv.y + vv.z + vv.w;
            s = __shfl(wave_reduce(s), 0, 64);
            float mean = s * (1.f / 256.f);
            float d0 = vv.x - mean, d1 = vv.y - mean, d2 = vv.z - mean, d3 = vv.w - mean;
            float ss = d0 * d0 + d1 * d1 + d2 * d2 + d3 * d3;
            ss = __shfl(wave_reduce(ss), 0, 64);
            float rstd = rsqrtf(ss * (1.f / 256.f) + 1e-5f);
            if (l == 0) { sRed[wv * 2] = mean; sRed[wv * 2 + 1] = rstd; }
        }
    }
    __syncthreads();
    for (int u = t; u < 256 * R; u += 1024) {
        int r = u >> 8, cc = u & 255;
        sH[r * 256 + cc] = (sO[r * 256 + cc] - sRed[r * 2]) * sRed[r * 2 + 1] * g2[cc] + b2[cc];
    }
    __syncthreads();

    // ---- FFN1 + exact GELU: K-half h (16 groups), cols {c2, c2+512} ----
    {
        int h = t >> 9, c2 = t & 511;
        float f0[R], f1[R];
#pragma unroll
        for (int r = 0; r < R; r++) { f0[r] = 0.f; f1[r] = 0.f; }
#pragma unroll 2
        for (int gg = 0; gg < 16; gg++) {
            int g = h * 16 + gg;
            uint4 wv0 = *(const uint4*)&pkF1[((unsigned)(g * 1024 + c2)) * 4];
            uint4 wv1 = *(const uint4*)&pkF1[((unsigned)(g * 1024 + c2 + 512)) * 4];
            float w0[8], w1[8]; unpack8(wv0, w0); unpack8(wv1, w1);
#pragma unroll
            for (int r = 0; r < R; r++) {
                float4 ha = ((const float4*)&sH[r * 256])[g * 2];
                float4 hb = ((const float4*)&sH[r * 256])[g * 2 + 1];
                f0[r] += dot8(ha, hb, w0); f1[r] += dot8(ha, hb, w1);
            }
        }
        float* dst = sX + h * (R * 1024);
#pragma unroll
        for (int r = 0; r < R; r++) {
            dst[r * 1024 + c2] = f0[r];
            dst[r * 1024 + c2 + 512] = f1[r];
        }
    }
    __syncthreads();
    {
        float bf = b_ffn1[t];
#pragma unroll
        for (int r = 0; r < R; r++) {
            float xx = sX[r * 1024 + t] + sX[R * 1024 + r * 1024 + t] + bf;
            sF[r * 1024 + t] = 0.5f * xx * (1.f + erff(xx * 0.70710678118654752f));
        }
    }
    __syncthreads();

    // ---- FFN2: K-eighth j8 (16 groups), cols {c7, c7+128} ----
    {
        float a0[R], a1[R];
#pragma unroll
        for (int r = 0; r < R; r++) { a0[r] = 0.f; a1[r] = 0.f; }
#pragma unroll 2
        for (int gg = 0; gg < 16; gg++) {
            int g = j8 * 16 + gg;
            uint4 wv0 = *(const uint4*)&pkF2[((unsigned)(g * 256 + c7)) * 4];
            uint4 wv1 = *(const uint4*)&pkF2[((unsigned)(g * 256 + c7 + 128)) * 4];
            float w0[8], w1[8]; unpack8(wv0, w0); unpack8(wv1, w1);
#pragma unroll
            for (int r = 0; r < R; r++) {
                float4 ha = ((const float4*)&sF[r * 1024])[g * 2];
                float4 hb = ((const float4*)&sF[r * 1024])[g * 2 + 1];
                a0[r] += dot8(ha, hb, w0); a1[r] += dot8(ha, hb, w1);
            }
        }
#pragma unroll
        for (int r = 0; r < R; r++) {
            sX[(j8 * R + r) * 256 + c7] = a0[r];
            sX[(j8 * R + r) * 256 + c7 + 128] = a1[r];
        }
    }
    __syncthreads();

    for (int u = t; u < 256 * R; u += 1024) {
        int r = u >> 8, cc = u & 255;
        float s = b_ffn2[cc];
#pragma unroll
        for (int jj = 0; jj < 8; jj++) s += sX[(jj * R + r) * 256 + cc];
        out[(size_t)(row0 + r) * Dd + cc] = sO[r * 256 + cc] + s;
    }
}

__global__ void __launch_bounds__(1024) k_out(const float* __restrict__ q,
                                              const float* __restrict__ agg,
                                              const unsigned* __restrict__ pkP,
                                              const float* __restrict__ b_proj,
                                              const float* __restrict__ g2,
                                              const float* __restrict__ b2,
                                              const unsigned* __restrict__ pkF1,
                                              const float* __restrict__ b_ffn1,
                                              const unsigned* __restrict__ pkF2,
                                              const float* __restrict__ b_ffn2,
                                              float* __restrict__ out) {
    __shared__ float sA[5 * 256];
    __shared__ float sO[5 * 256];
    __shared__ float sH[5 * 256];
    __shared__ float sF[5 * 1024];
    __shared__ float sX[10240];       // partial buffer: proj/FFN2 8x, FFN1 2x splits
    __shared__ float sRed[16];
    __shared__ float pad[1600];       // inflate LDS past 80KB -> exactly 1 block/CU
    if (b_ffn2 == nullptr) pad[threadIdx.x & 1023] = 0.f;   // keeps pad alive; never executes

    int bid = blockIdx.x;
    if (bid < 176) {
        out_body<5>(bid * 5, q, agg, pkP, b_proj, g2, b2, pkF1, b_ffn1, pkF2, b_ffn2,
                    out, sA, sO, sH, sF, sX, sRed);
    } else {
        out_body<4>(880 + (bid - 176) * 4, q, agg, pkP, b_proj, g2, b2, pkF1, b_ffn1,
                    pkF2, b_ffn2, out, sA, sO, sH, sF, sX, sRed);
    }
}

// ---------------- launcher ----------------
extern "C" void kernel_launch(void* const* d_in, const int* in_sizes, int n_in,
                              void* d_out, int out_size, void* d_ws, size_t ws_size,
                              hipStream_t stream) {
    const float* q        = (const float*)d_in[0];
    const float* kv_feats = (const float*)d_in[1];
    const unsigned char* kv_mask = (const unsigned char*)d_in[2];
    const float* delta_sec= (const float*)d_in[3];
    const float* w_ref    = (const float*)d_in[4];
    const float* b_ref    = (const float*)d_in[5];
    const float* w_delta  = (const float*)d_in[6];
    const float* b_delta  = (const float*)d_in[7];
    const float* w_alpha  = (const float*)d_in[8];
    const float* b_alpha  = (const float*)d_in[9];
    // d_in[10] = lam: softmax shift-invariance makes it a no-op
    const float* w_proj   = (const float*)d_in[11];
    const float* b_proj   = (const float*)d_in[12];
    const float* ln1_g    = (const float*)d_in[13];
    const float* ln1_b    = (const float*)d_in[14];
    const float* ln2_g    = (const float*)d_in[15];
    const float* ln2_b    = (const float*)d_in[16];
    const float* w_ffn1   = (const float*)d_in[17];
    const float* b_ffn1   = (const float*)d_in[18];
    const float* w_ffn2   = (const float*)d_in[19];
    const float* b_ffn2   = (const float*)d_in[20];
    const float* w_rel    = (const float*)d_in[21];
    const float* b_rel    = (const float*)d_in[22];
    float* out = (float*)d_out;

    unsigned* pk   = (unsigned*)d_ws;                  // 294912 uints
    unsigned* pkP  = pk;
    unsigned* pkF1 = pk + 32768;
    unsigned* pkF2 = pk + 163840;
    float*    agg  = (float*)(pk + 294912);            // 307200 floats

    const int BQ = Bn * Qn;                            // 1200
    k_front<<<dim3(576 + BQ), dim3(512), 0, stream>>>(w_proj, w_ffn1, w_ffn2, pk,
                                                      q, ln1_g, ln1_b, w_ref, b_ref,
                                                      delta_sec, w_rel, b_rel,
                                                      w_delta, b_delta, w_alpha, b_alpha,
                                                      kv_mask, kv_feats, agg);
    k_out<<<dim3(256), dim3(1024), 0, stream>>>(q, agg, pkP, b_proj, ln2_g, ln2_b,
                                                pkF1, b_ffn1, pkF2, b_ffn2, out);
}

// Round 3
// 294.365 us; speedup vs baseline: 1.1533x; 1.1533x over previous
//
#include <hip/hip_runtime.h>
#include <math.h>

#define Bn 4
#define Qn 300
#define WL 8
#define Hh 64
#define Ww 64
#define Dd 256
#define Mm 4

// ---------------- helpers ----------------
__device__ __forceinline__ float wave_reduce(float v) {
#pragma unroll
    for (int off = 32; off > 0; off >>= 1) v += __shfl_down(v, off, 64);
    return v;
}

__device__ __forceinline__ float lo16(unsigned u) { return __uint_as_float(u << 16); }
__device__ __forceinline__ float hi16(unsigned u) { return __uint_as_float(u & 0xffff0000u); }

__device__ __forceinline__ unsigned bfp(float a, float b) {
    unsigned ua = __float_as_uint(a); ua = (ua + 0x7fffu + ((ua >> 16) & 1u)) >> 16;
    unsigned ub = __float_as_uint(b); ub = (ub + 0x7fffu + ((ub >> 16) & 1u)) >> 16;
    return ua | (ub << 16);
}

__device__ __forceinline__ void unpack8(uint4 wv, float* w) {
    w[0] = lo16(wv.x); w[1] = hi16(wv.x); w[2] = lo16(wv.y); w[3] = hi16(wv.y);
    w[4] = lo16(wv.z); w[5] = hi16(wv.z); w[6] = lo16(wv.w); w[7] = hi16(wv.w);
}

__device__ __forceinline__ float dot8(float4 ha, float4 hb, const float* w) {
    return ha.x * w[0] + ha.y * w[1] + ha.z * w[2] + ha.w * w[3]
         + hb.x * w[4] + hb.y * w[5] + hb.z * w[6] + hb.w * w[7];
}

// ---------------- kernel 1: pack (blocks 0..575) + fused params+gather (576..1775) ----------------
// params phase computes LN1/PE/rel/point-params into LDS records, gather phase consumes
// them directly. LDS overlay: Prec+part live inside WcT's storage (dead after dot phase)
// -> 46KB -> 3 blocks/CU (LDS-limited). launch_bounds(512,4): do NOT cap VGPRs harder --
// (512,6) forced 40 VGPRs and spilled wr[64] to scratch (103MB writes, +36us).
__global__ void __launch_bounds__(512, 4) k_front(const float* __restrict__ wp,
                                                  const float* __restrict__ wf1,
                                                  const float* __restrict__ wf2,
                                                  unsigned* __restrict__ pk,
                                                  const float* __restrict__ q,
                                                  const float* __restrict__ g1,
                                                  const float* __restrict__ b1,
                                                  const float* __restrict__ w_ref,
                                                  const float* __restrict__ b_ref,
                                                  const float* __restrict__ dsec,
                                                  const float* __restrict__ w_rel,
                                                  const float* __restrict__ b_rel,
                                                  const float* __restrict__ w_delta,
                                                  const float* __restrict__ b_delta,
                                                  const float* __restrict__ w_alpha,
                                                  const float* __restrict__ b_alpha,
                                                  const unsigned char* __restrict__ mask,
                                                  const float* __restrict__ feats,
                                                  float* __restrict__ agg) {
    int bid = blockIdx.x, t = threadIdx.x;

    if (bid < 576) {
        // ---------------- weight packing path (576*512 = 294912 elems) ----------------
        int i = bid * 512 + t;
        if (i < 32768) {                     // pkP: K=256 (g<32), N=256
            int p = i & 3, c = (i >> 2) & 255, g = i >> 10;
            pk[i] = bfp(wp[(g * 8 + 2 * p) * 256 + c], wp[(g * 8 + 2 * p + 1) * 256 + c]);
        } else if (i < 163840) {             // pkF1: K=256 (g<32), N=1024
            int i2 = i - 32768;
            int p = i2 & 3, c = (i2 >> 2) & 1023, g = i2 >> 12;
            pk[i] = bfp(wf1[(g * 8 + 2 * p) * 1024 + c], wf1[(g * 8 + 2 * p + 1) * 1024 + c]);
        } else {                             // pkF2: K=1024 (g<128), N=256
            int i3 = i - 163840;
            int p = i3 & 3, c = (i3 >> 2) & 255, g = i3 >> 10;
            pk[i] = bfp(wf2[(g * 8 + 2 * p) * 256 + c], wf2[(g * 8 + 2 * p + 1) * 256 + c]);
        }
        return;
    }

    __shared__ float sqn[256];
    __shared__ float pe[8][64];
    __shared__ float rel[8][260];     // +4 pad: 16B-aligned float4 rows
    __shared__ __align__(16) float WcT[16 * 516];   // WcT[jj][k], row stride 516
    __shared__ float dres[2][8][16];
    __shared__ float res[8][16];
    __shared__ float red[16];
    __shared__ float sref[2];
    // ---- overlay: WcT is dead after the 16-dot phase; reuse its storage ----
    float (*part)[256] = (float (*)[256])WcT;        // 8*256 floats = 8KB at offset 0
    unsigned* Prec = (unsigned*)(WcT + 2048);        // 32*16 uints = 2KB at offset 8KB

    int bq = bid - 576;
    int ch = t & 255;
    bool lo = t < 256;
    int lane = t & 63, wv = t >> 6;

    // ---- early independent loads: w_rel column in registers (both halves) ----
    float wr[64];
#pragma unroll
    for (int k = 0; k < 64; k++) wr[k] = w_rel[k * Dd + ch];

    // ---- stage combined delta/alpha weights into LDS (transposed), 512 threads ----
    for (int u = t; u < 512 * 16; u += 512) {
        int k = u >> 4, jj = u & 15;
        float w = (jj < 12) ? w_delta[k * 12 + jj] : w_alpha[k * 4 + (jj - 12)];
        WcT[jj * 516 + k] = w;
    }

    // ---- LN1 (channels on threads 0..255) ----
    float x = lo ? q[bq * Dd + ch] : 0.f;
    float sm = wave_reduce(x);
    if (lane == 0) red[wv] = sm;
    __syncthreads();
    float m = (red[0] + red[1] + red[2] + red[3] + red[4] + red[5] + red[6] + red[7]) * (1.f / Dd);
    __syncthreads();
    float dx = lo ? (x - m) : 0.f;
    float sv = wave_reduce(dx * dx);
    if (lane == 0) red[wv] = sv;
    __syncthreads();
    float v = (red[0] + red[1] + red[2] + red[3] + red[4] + red[5] + red[6] + red[7]) * (1.f / Dd);
    __syncthreads();
    float y = 0.f;
    if (lo) { y = dx * rsqrtf(v + 1e-5f) * g1[ch] + b1[ch]; sqn[ch] = y; }

    // ---- sinusoidal PE for all 8 windows ----
    if (lo) {
        int wl = t >> 5, i2 = t & 31;
        float f = expf(-logf(10000.f) * (float)i2 * (1.f / 32.f));
        float a = dsec[bq * WL + wl] * f;
        pe[wl][i2] = sinf(a);
        pe[wl][i2 + 32] = cosf(a);
    }

    // ---- ref = sigmoid(qn @ w_ref + b_ref), both columns in one barrier ----
    float c0 = lo ? y * w_ref[2 * ch] : 0.f;
    float c1 = lo ? y * w_ref[2 * ch + 1] : 0.f;
    c0 = wave_reduce(c0); c1 = wave_reduce(c1);
    if (lane == 0) { red[wv] = c0; red[8 + wv] = c1; }
    __syncthreads();                 // also publishes pe
    if (t == 0) {
        float s0 = red[0] + red[1] + red[2] + red[3] + red[4] + red[5] + red[6] + red[7] + b_ref[0];
        float s1 = red[8] + red[9] + red[10] + red[11] + red[12] + red[13] + red[14] + red[15] + b_ref[1];
        sref[0] = 1.f / (1.f + expf(-s0));
        sref[1] = 1.f / (1.f + expf(-s1));
    }

    // ---- rel_feat: half-block per 4 windows (pe via float4 broadcast reads) ----
    {
        float brl = b_rel[ch];
        int wh = t >> 8;
#pragma unroll
        for (int w2 = 0; w2 < 4; w2++) {
            int wl = wh * 4 + w2;
            const float4* p4 = (const float4*)&pe[wl][0];
            float r = brl;
#pragma unroll
            for (int k4 = 0; k4 < 16; k4++) {
                float4 p = p4[k4];
                r += p.x * wr[4 * k4] + p.y * wr[4 * k4 + 1]
                   + p.z * wr[4 * k4 + 2] + p.w * wr[4 * k4 + 3];
            }
            rel[wl][ch] = r;
        }
    }
    __syncthreads();                 // publishes rel, WcT, sqn

    // ---- 16 dot products per window, K split in halves over 256 threads ----
    if (t < 256) {
        int h = t >> 7, idx = t & 127, wl = idx >> 4, jj = idx & 15;
        const float4* wrow = (const float4*)&WcT[jj * 516 + h * 256];
        const float4* arow = h ? (const float4*)&rel[wl][0] : (const float4*)sqn;
        float s = 0.f;
#pragma unroll 8
        for (int k4 = 0; k4 < 64; k4++) {
            float4 a = arow[k4], w = wrow[k4];
            s += a.x * w.x + a.y * w.y + a.z * w.z + a.w * w.w;
        }
        dres[h][wl][jj] = s;
    }
    __syncthreads();                 // WcT dead from here on
    if (t < 128) {
        int wl = t >> 4, jj = t & 15;
        res[wl][jj] = dres[0][wl][jj] + dres[1][wl][jj]
                    + ((jj < 12) ? b_delta[jj] : b_alpha[jj - 12]);
    }
    __syncthreads();

    // ---- per-point records into LDS (Prec overlays WcT storage) ----
    if (t < 32) {
        int wl = t >> 2, mm = t & 3;
        float l0 = res[wl][12], l1 = res[wl][13], l2 = res[wl][14], l3 = res[wl][15];
        float mx = fmaxf(fmaxf(l0, l1), fmaxf(l2, l3));
        float inv = 1.f / (expf(l0 - mx) + expf(l1 - mx) + expf(l2 - mx) + expf(l3 - mx));
        // -lam_sp*|dsec| shift is constant across M -> drops out of softmax
        float wgt = expf(res[wl][12 + mm] - mx) * inv;

        float cx = fminf(fmaxf(sref[0] + tanhf(res[wl][mm * 3 + 0]), 0.f), 1.f);
        float cy = fminf(fmaxf(sref[1] + tanhf(res[wl][mm * 3 + 1]), 0.f), 1.f);
        float tgt = (float)wl + tanhf(res[wl][mm * 3 + 2]);
        float t0f = fminf(fmaxf(floorf(tgt), 0.f), (float)(WL - 1));
        float t1f = fminf(t0f + 1.f, (float)(WL - 1));
        float alpha = tgt - t0f;
        float px = cx * (float)Ww - 0.5f, py = cy * (float)Hh - 0.5f;
        float fx = floorf(px), fy = floorf(py);
        float wx = px - fx, wy = py - fy;
        int X0 = (int)fminf(fmaxf(fx, 0.f), (float)(Ww - 1));
        int X1 = (int)fminf(fmaxf(fx + 1.f, 0.f), (float)(Ww - 1));
        int Y0 = (int)fminf(fmaxf(fy, 0.f), (float)(Hh - 1));
        int Y1 = (int)fminf(fmaxf(fy + 1.f, 0.f), (float)(Hh - 1));
        int T0 = (int)t0f, T1 = (int)t1f;

        float w00 = (1.f - wy) * (1.f - wx), w01 = (1.f - wy) * wx;
        float w10 = wy * (1.f - wx), w11 = wy * wx;
        float wt0 = wgt * (1.f - alpha), wt1 = wgt * alpha;

        int b = bq / Qn;
        int base0 = (b * WL + T0) * Hh;
        int base1 = (b * WL + T1) * Hh;
        int i00 = (base0 + Y0) * Ww + X0, i01 = (base0 + Y0) * Ww + X1;
        int i10 = (base0 + Y1) * Ww + X0, i11 = (base0 + Y1) * Ww + X1;
        int j00 = (base1 + Y0) * Ww + X0, j01 = (base1 + Y0) * Ww + X1;
        int j10 = (base1 + Y1) * Ww + X0, j11 = (base1 + Y1) * Ww + X1;

        unsigned* rec = &Prec[t * 16];
        rec[0] = __float_as_uint(wt0 * w00 * (mask[i00] ? 0.f : 1.f));
        rec[1] = __float_as_uint(wt0 * w01 * (mask[i01] ? 0.f : 1.f));
        rec[2] = __float_as_uint(wt0 * w10 * (mask[i10] ? 0.f : 1.f));
        rec[3] = __float_as_uint(wt0 * w11 * (mask[i11] ? 0.f : 1.f));
        rec[4] = __float_as_uint(wt1 * w00 * (mask[j00] ? 0.f : 1.f));
        rec[5] = __float_as_uint(wt1 * w01 * (mask[j01] ? 0.f : 1.f));
        rec[6] = __float_as_uint(wt1 * w10 * (mask[j10] ? 0.f : 1.f));
        rec[7] = __float_as_uint(wt1 * w11 * (mask[j11] ? 0.f : 1.f));
        rec[8] = i00; rec[9] = i01; rec[10] = i10; rec[11] = i11;
        rec[12] = j00; rec[13] = j01; rec[14] = j10; rec[15] = j11;
    }
    __syncthreads();

    // ---- gather + weighted aggregation (wave j owns points 4j..4j+3) ----
    {
        const float4* f4 = (const float4*)feats;
        int j = t >> 6;
        float4 acc = {0.f, 0.f, 0.f, 0.f};
#pragma unroll
        for (int p = 0; p < 4; p++) {
            const unsigned* rec = &Prec[(j * 4 + p) * 16];
#pragma unroll
            for (int cn = 0; cn < 8; cn++) {
                float w = __uint_as_float(rec[cn]);
                size_t idx = rec[8 + cn];
                float4 vv = f4[idx * 64 + lane];
                acc.x += w * vv.x; acc.y += w * vv.y; acc.z += w * vv.z; acc.w += w * vv.w;
            }
        }
        ((float4*)&part[j][0])[lane] = acc;
    }
    __syncthreads();
    if (t < 256) {
        agg[(size_t)bq * Dd + t] = part[0][t] + part[1][t] + part[2][t] + part[3][t]
                                 + part[4][t] + part[5][t] + part[6][t] + part[7][t];
    }
}

// ---------------- kernel 2: proj + residual + LN2 + FFN (+residual) ----------------
// 256 blocks x 1024 threads, 1 block/CU. Each GEMM phase: thread owns 2 columns x a
// K-slice; activation LDS broadcasts amortize over both columns (720 -> 360 b128/thread).
template<int R>
__device__ __forceinline__ void out_body(int row0,
        const float* __restrict__ q, const float* __restrict__ agg,
        const unsigned* __restrict__ pkP, const float* __restrict__ b_proj,
        const float* __restrict__ g2, const float* __restrict__ b2,
        const unsigned* __restrict__ pkF1, const float* __restrict__ b_ffn1,
        const unsigned* __restrict__ pkF2, const float* __restrict__ b_ffn2,
        float* __restrict__ out,
        float* sA, float* sO, float* sH, float* sF, float* sX, float* sRed) {
    int t = threadIdx.x;
    int j8 = t >> 7, c7 = t & 127;

    for (int u = t; u < 256 * R; u += 1024) {
        int r = u >> 8, cc = u & 255;
        sA[r * 256 + cc] = agg[(size_t)(row0 + r) * Dd + cc];
    }
    __syncthreads();

    // ---- proj: K-eighth j8 (4 groups), cols {c7, c7+128} ----
    {
        float a0[R], a1[R];
#pragma unroll
        for (int r = 0; r < R; r++) { a0[r] = 0.f; a1[r] = 0.f; }
#pragma unroll
        for (int gg = 0; gg < 4; gg++) {
            int g = j8 * 4 + gg;
            uint4 wv0 = *(const uint4*)&pkP[((unsigned)(g * 256 + c7)) * 4];
            uint4 wv1 = *(const uint4*)&pkP[((unsigned)(g * 256 + c7 + 128)) * 4];
            float w0[8], w1[8]; unpack8(wv0, w0); unpack8(wv1, w1);
#pragma unroll
            for (int r = 0; r < R; r++) {
                float4 ha = ((const float4*)&sA[r * 256])[g * 2];
                float4 hb = ((const float4*)&sA[r * 256])[g * 2 + 1];
                a0[r] += dot8(ha, hb, w0); a1[r] += dot8(ha, hb, w1);
            }
        }
#pragma unroll
        for (int r = 0; r < R; r++) {
            sX[(j8 * R + r) * 256 + c7] = a0[r];
            sX[(j8 * R + r) * 256 + c7 + 128] = a1[r];
        }
    }
    __syncthreads();

    // ---- combine + residual ----
    for (int u = t; u < 256 * R; u += 1024) {
        int r = u >> 8, cc = u & 255;
        float o = q[(size_t)(row0 + r) * Dd + cc] + b_proj[cc];
#pragma unroll
        for (int jj = 0; jj < 8; jj++) o += sX[(jj * R + r) * 256 + cc];
        sO[r * 256 + cc] = o;
    }
    __syncthreads();

    // ---- LN2: wave r reduces row r ----
    {
        int wv = t >> 6, l = t & 63;
        if (wv < R) {
            float4 vv = ((const float4*)&sO[wv * 256])[l];
            float s = vv.x + vv.y + vv.z + vv.w;
            s = __shfl(wave_reduce(s), 0, 64);
            float mean = s * (1.f / 256.f);
            float d0 = vv.x - mean, d1 = vv.y - mean, d2 = vv.z - mean, d3 = vv.w - mean;
            float ss = d0 * d0 + d1 * d1 + d2 * d2 + d3 * d3;
            ss = __shfl(wave_reduce(ss), 0, 64);
            float rstd = rsqrtf(ss * (1.f / 256.f) + 1e-5f);
            if (l == 0) { sRed[wv * 2] = mean; sRed[wv * 2 + 1] = rstd; }
        }
    }
    __syncthreads();
    for (int u = t; u < 256 * R; u += 1024) {
        int r = u >> 8, cc = u & 255;
        sH[r * 256 + cc] = (sO[r * 256 + cc] - sRed[r * 2]) * sRed[r * 2 + 1] * g2[cc] + b2[cc];
    }
    __syncthreads();

    // ---- FFN1 + exact GELU: K-half h (16 groups), cols {c2, c2+512} ----
    {
        int h = t >> 9, c2 = t & 511;
        float f0[R], f1[R];
#pragma unroll
        for (int r = 0; r < R; r++) { f0[r] = 0.f; f1[r] = 0.f; }
#pragma unroll 2
        for (int gg = 0; gg < 16; gg++) {
            int g = h * 16 + gg;
            uint4 wv0 = *(const uint4*)&pkF1[((unsigned)(g * 1024 + c2)) * 4];
            uint4 wv1 = *(const uint4*)&pkF1[((unsigned)(g * 1024 + c2 + 512)) * 4];
            float w0[8], w1[8]; unpack8(wv0, w0); unpack8(wv1, w1);
#pragma unroll
            for (int r = 0; r < R; r++) {
                float4 ha = ((const float4*)&sH[r * 256])[g * 2];
                float4 hb = ((const float4*)&sH[r * 256])[g * 2 + 1];
                f0[r] += dot8(ha, hb, w0); f1[r] += dot8(ha, hb, w1);
            }
        }
        float* dst = sX + h * (R * 1024);
#pragma unroll
        for (int r = 0; r < R; r++) {
            dst[r * 1024 + c2] = f0[r];
            dst[r * 1024 + c2 + 512] = f1[r];
        }
    }
    __syncthreads();
    {
        float bf = b_ffn1[t];
#pragma unroll
        for (int r = 0; r < R; r++) {
            float xx = sX[r * 1024 + t] + sX[R * 1024 + r * 1024 + t] + bf;
            sF[r * 1024 + t] = 0.5f * xx * (1.f + erff(xx * 0.70710678118654752f));
        }
    }
    __syncthreads();

    // ---- FFN2: K-eighth j8 (16 groups), cols {c7, c7+128} ----
    {
        float a0[R], a1[R];
#pragma unroll
        for (int r = 0; r < R; r++) { a0[r] = 0.f; a1[r] = 0.f; }
#pragma unroll 2
        for (int gg = 0; gg < 16; gg++) {
            int g = j8 * 16 + gg;
            uint4 wv0 = *(const uint4*)&pkF2[((unsigned)(g * 256 + c7)) * 4];
            uint4 wv1 = *(const uint4*)&pkF2[((unsigned)(g * 256 + c7 + 128)) * 4];
            float w0[8], w1[8]; unpack8(wv0, w0); unpack8(wv1, w1);
#pragma unroll
            for (int r = 0; r < R; r++) {
                float4 ha = ((const float4*)&sF[r * 1024])[g * 2];
                float4 hb = ((const float4*)&sF[r * 1024])[g * 2 + 1];
                a0[r] += dot8(ha, hb, w0); a1[r] += dot8(ha, hb, w1);
            }
        }
#pragma unroll
        for (int r = 0; r < R; r++) {
            sX[(j8 * R + r) * 256 + c7] = a0[r];
            sX[(j8 * R + r) * 256 + c7 + 128] = a1[r];
        }
    }
    __syncthreads();

    for (int u = t; u < 256 * R; u += 1024) {
        int r = u >> 8, cc = u & 255;
        float s = b_ffn2[cc];
#pragma unroll
        for (int jj = 0; jj < 8; jj++) s += sX[(jj * R + r) * 256 + cc];
        out[(size_t)(row0 + r) * Dd + cc] = sO[r * 256 + cc] + s;
    }
}

__global__ void __launch_bounds__(1024) k_out(const float* __restrict__ q,
                                              const float* __restrict__ agg,
                                              const unsigned* __restrict__ pkP,
                                              const float* __restrict__ b_proj,
                                              const float* __restrict__ g2,
                                              const float* __restrict__ b2,
                                              const unsigned* __restrict__ pkF1,
                                              const float* __restrict__ b_ffn1,
                                              const unsigned* __restrict__ pkF2,
                                              const float* __restrict__ b_ffn2,
                                              float* __restrict__ out) {
    __shared__ float sA[5 * 256];
    __shared__ float sO[5 * 256];
    __shared__ float sH[5 * 256];
    __shared__ float sF[5 * 1024];
    __shared__ float sX[10240];       // partial buffer: proj/FFN2 8x, FFN1 2x splits
    __shared__ float sRed[16];
    __shared__ float pad[1600];       // inflate LDS past 80KB -> exactly 1 block/CU
    if (b_ffn2 == nullptr) pad[threadIdx.x & 1023] = 0.f;   // keeps pad alive; never executes

    int bid = blockIdx.x;
    if (bid < 176) {
        out_body<5>(bid * 5, q, agg, pkP, b_proj, g2, b2, pkF1, b_ffn1, pkF2, b_ffn2,
                    out, sA, sO, sH, sF, sX, sRed);
    } else {
        out_body<4>(880 + (bid - 176) * 4, q, agg, pkP, b_proj, g2, b2, pkF1, b_ffn1,
                    pkF2, b_ffn2, out, sA, sO, sH, sF, sX, sRed);
    }
}

// ---------------- launcher ----------------
extern "C" void kernel_launch(void* const* d_in, const int* in_sizes, int n_in,
                              void* d_out, int out_size, void* d_ws, size_t ws_size,
                              hipStream_t stream) {
    const float* q        = (const float*)d_in[0];
    const float* kv_feats = (const float*)d_in[1];
    const unsigned char* kv_mask = (const unsigned char*)d_in[2];
    const float* delta_sec= (const float*)d_in[3];
    const float* w_ref    = (const float*)d_in[4];
    const float* b_ref    = (const float*)d_in[5];
    const float* w_delta  = (const float*)d_in[6];
    const float* b_delta  = (const float*)d_in[7];
    const float* w_alpha  = (const float*)d_in[8];
    const float* b_alpha  = (const float*)d_in[9];
    // d_in[10] = lam: softmax shift-invariance makes it a no-op
    const float* w_proj   = (const float*)d_in[11];
    const float* b_proj   = (const float*)d_in[12];
    const float* ln1_g    = (const float*)d_in[13];
    const float* ln1_b    = (const float*)d_in[14];
    const float* ln2_g    = (const float*)d_in[15];
    const float* ln2_b    = (const float*)d_in[16];
    const float* w_ffn1   = (const float*)d_in[17];
    const float* b_ffn1   = (const float*)d_in[18];
    const float* w_ffn2   = (const float*)d_in[19];
    const float* b_ffn2   = (const float*)d_in[20];
    const float* w_rel    = (const float*)d_in[21];
    const float* b_rel    = (const float*)d_in[22];
    float* out = (float*)d_out;

    unsigned* pk   = (unsigned*)d_ws;                  // 294912 uints
    unsigned* pkP  = pk;
    unsigned* pkF1 = pk + 32768;
    unsigned* pkF2 = pk + 163840;
    float*    agg  = (float*)(pk + 294912);            // 307200 floats

    const int BQ = Bn * Qn;                            // 1200
    k_front<<<dim3(576 + BQ), dim3(512), 0, stream>>>(w_proj, w_ffn1, w_ffn2, pk,
                                                      q, ln1_g, ln1_b, w_ref, b_ref,
                                                      delta_sec, w_rel, b_rel,
                                                      w_delta, b_delta, w_alpha, b_alpha,
                                                      kv_mask, kv_feats, agg);
    k_out<<<dim3(256), dim3(1024), 0, stream>>>(q, agg, pkP, b_proj, ln2_g, ln2_b,
                                                pkF1, b_ffn1, pkF2, b_ffn2, out);
}

// Round 5
// 278.250 us; speedup vs baseline: 1.2201x; 1.0579x over previous
//
#include <hip/hip_runtime.h>
#include <math.h>

#define Bn 4
#define Qn 300
#define WL 8
#define Hh 64
#define Ww 64
#define Dd 256
#define Mm 4

// ---------------- helpers ----------------
__device__ __forceinline__ float wave_reduce(float v) {
#pragma unroll
    for (int off = 32; off > 0; off >>= 1) v += __shfl_down(v, off, 64);
    return v;
}

// f16x2 pack/dot helpers (v_cvt_pkrtz_f16_f32 + v_dot2_f32_f16)
using h2_t = _Float16 __attribute__((ext_vector_type(2)));

__device__ __forceinline__ unsigned packh2(float a, float b) {
    auto h = __builtin_amdgcn_cvt_pkrtz(a, b);          // __fp16 ext_vector_type(2)
    union { decltype(h) h; unsigned u; } x; x.h = h; return x.u;
}

__device__ __forceinline__ h2_t u2h2(unsigned u) {
    union { unsigned u; h2_t h; } x; x.u = u; return x.h;
}

__device__ __forceinline__ float dot2p(unsigned a, unsigned w, float acc) {
#if __has_builtin(__builtin_amdgcn_fdot2)
    return __builtin_amdgcn_fdot2(u2h2(a), u2h2(w), acc, false);
#else
    h2_t A = u2h2(a), W = u2h2(w);
    return acc + (float)A.x * (float)W.x + (float)A.y * (float)W.y;
#endif
}

__device__ __forceinline__ float dot8h(uint4 av, uint4 wv, float acc) {
    acc = dot2p(av.x, wv.x, acc);
    acc = dot2p(av.y, wv.y, acc);
    acc = dot2p(av.z, wv.z, acc);
    acc = dot2p(av.w, wv.w, acc);
    return acc;
}

// ---------------- kernel 1: pack (blocks 0..575) + fused params+gather (576..1775) ----------------
// params phase computes LN1/PE/rel/point-params into LDS records, gather phase consumes
// them directly. LDS overlay: Prec+part live inside WcT's storage (dead after dot phase)
// -> 46KB -> 3 blocks/CU (LDS-limited). launch_bounds(512,4): do NOT cap VGPRs harder --
// (512,6) forced 40 VGPRs and spilled wr[64] to scratch (103MB writes, +36us).
__global__ void __launch_bounds__(512, 4) k_front(const float* __restrict__ wp,
                                                  const float* __restrict__ wf1,
                                                  const float* __restrict__ wf2,
                                                  unsigned* __restrict__ pk,
                                                  const float* __restrict__ q,
                                                  const float* __restrict__ g1,
                                                  const float* __restrict__ b1,
                                                  const float* __restrict__ w_ref,
                                                  const float* __restrict__ b_ref,
                                                  const float* __restrict__ dsec,
                                                  const float* __restrict__ w_rel,
                                                  const float* __restrict__ b_rel,
                                                  const float* __restrict__ w_delta,
                                                  const float* __restrict__ b_delta,
                                                  const float* __restrict__ w_alpha,
                                                  const float* __restrict__ b_alpha,
                                                  const unsigned char* __restrict__ mask,
                                                  const float* __restrict__ feats,
                                                  float* __restrict__ agg) {
    int bid = blockIdx.x, t = threadIdx.x;

    if (bid < 576) {
        // ---------------- weight packing path (576*512 = 294912 elems), f16 pairs ----------------
        int i = bid * 512 + t;
        if (i < 32768) {                     // pkP: K=256 (g<32), N=256
            int p = i & 3, c = (i >> 2) & 255, g = i >> 10;
            pk[i] = packh2(wp[(g * 8 + 2 * p) * 256 + c], wp[(g * 8 + 2 * p + 1) * 256 + c]);
        } else if (i < 163840) {             // pkF1: K=256 (g<32), N=1024
            int i2 = i - 32768;
            int p = i2 & 3, c = (i2 >> 2) & 1023, g = i2 >> 12;
            pk[i] = packh2(wf1[(g * 8 + 2 * p) * 1024 + c], wf1[(g * 8 + 2 * p + 1) * 1024 + c]);
        } else {                             // pkF2: K=1024 (g<128), N=256
            int i3 = i - 163840;
            int p = i3 & 3, c = (i3 >> 2) & 255, g = i3 >> 10;
            pk[i] = packh2(wf2[(g * 8 + 2 * p) * 256 + c], wf2[(g * 8 + 2 * p + 1) * 256 + c]);
        }
        return;
    }

    __shared__ float sqn[256];
    __shared__ float pe[8][64];
    __shared__ float rel[8][260];     // +4 pad: 16B-aligned float4 rows
    __shared__ __align__(16) float WcT[16 * 516];   // WcT[jj][k], row stride 516
    __shared__ float dres[2][8][16];
    __shared__ float res[8][16];
    __shared__ float red[16];
    __shared__ float sref[2];
    // ---- overlay: WcT is dead after the 16-dot phase; reuse its storage ----
    float (*part)[256] = (float (*)[256])WcT;        // 8*256 floats = 8KB at offset 0
    unsigned* Prec = (unsigned*)(WcT + 2048);        // 32*16 uints = 2KB at offset 8KB

    int bq = bid - 576;
    int ch = t & 255;
    bool lo = t < 256;
    int lane = t & 63, wv = t >> 6;

    // ---- early independent loads: w_rel column in registers (both halves) ----
    float wr[64];
#pragma unroll
    for (int k = 0; k < 64; k++) wr[k] = w_rel[k * Dd + ch];

    // ---- stage combined delta/alpha weights into LDS (transposed), 512 threads ----
    for (int u = t; u < 512 * 16; u += 512) {
        int k = u >> 4, jj = u & 15;
        float w = (jj < 12) ? w_delta[k * 12 + jj] : w_alpha[k * 4 + (jj - 12)];
        WcT[jj * 516 + k] = w;
    }

    // ---- LN1 (channels on threads 0..255) ----
    float x = lo ? q[bq * Dd + ch] : 0.f;
    float sm = wave_reduce(x);
    if (lane == 0) red[wv] = sm;
    __syncthreads();
    float m = (red[0] + red[1] + red[2] + red[3] + red[4] + red[5] + red[6] + red[7]) * (1.f / Dd);
    __syncthreads();
    float dx = lo ? (x - m) : 0.f;
    float sv = wave_reduce(dx * dx);
    if (lane == 0) red[wv] = sv;
    __syncthreads();
    float v = (red[0] + red[1] + red[2] + red[3] + red[4] + red[5] + red[6] + red[7]) * (1.f / Dd);
    __syncthreads();
    float y = 0.f;
    if (lo) { y = dx * rsqrtf(v + 1e-5f) * g1[ch] + b1[ch]; sqn[ch] = y; }

    // ---- sinusoidal PE for all 8 windows ----
    if (lo) {
        int wl = t >> 5, i2 = t & 31;
        float f = expf(-logf(10000.f) * (float)i2 * (1.f / 32.f));
        float a = dsec[bq * WL + wl] * f;
        pe[wl][i2] = sinf(a);
        pe[wl][i2 + 32] = cosf(a);
    }

    // ---- ref = sigmoid(qn @ w_ref + b_ref), both columns in one barrier ----
    float c0 = lo ? y * w_ref[2 * ch] : 0.f;
    float c1 = lo ? y * w_ref[2 * ch + 1] : 0.f;
    c0 = wave_reduce(c0); c1 = wave_reduce(c1);
    if (lane == 0) { red[wv] = c0; red[8 + wv] = c1; }
    __syncthreads();                 // also publishes pe
    if (t == 0) {
        float s0 = red[0] + red[1] + red[2] + red[3] + red[4] + red[5] + red[6] + red[7] + b_ref[0];
        float s1 = red[8] + red[9] + red[10] + red[11] + red[12] + red[13] + red[14] + red[15] + b_ref[1];
        sref[0] = 1.f / (1.f + expf(-s0));
        sref[1] = 1.f / (1.f + expf(-s1));
    }

    // ---- rel_feat: half-block per 4 windows (pe via float4 broadcast reads) ----
    {
        float brl = b_rel[ch];
        int wh = t >> 8;
#pragma unroll
        for (int w2 = 0; w2 < 4; w2++) {
            int wl = wh * 4 + w2;
            const float4* p4 = (const float4*)&pe[wl][0];
            float r = brl;
#pragma unroll
            for (int k4 = 0; k4 < 16; k4++) {
                float4 p = p4[k4];
                r += p.x * wr[4 * k4] + p.y * wr[4 * k4 + 1]
                   + p.z * wr[4 * k4 + 2] + p.w * wr[4 * k4 + 3];
            }
            rel[wl][ch] = r;
        }
    }
    __syncthreads();                 // publishes rel, WcT, sqn

    // ---- 16 dot products per window, K split in halves over 256 threads ----
    if (t < 256) {
        int h = t >> 7, idx = t & 127, wl = idx >> 4, jj = idx & 15;
        const float4* wrow = (const float4*)&WcT[jj * 516 + h * 256];
        const float4* arow = h ? (const float4*)&rel[wl][0] : (const float4*)sqn;
        float s = 0.f;
#pragma unroll 8
        for (int k4 = 0; k4 < 64; k4++) {
            float4 a = arow[k4], w = wrow[k4];
            s += a.x * w.x + a.y * w.y + a.z * w.z + a.w * w.w;
        }
        dres[h][wl][jj] = s;
    }
    __syncthreads();                 // WcT dead from here on
    if (t < 128) {
        int wl = t >> 4, jj = t & 15;
        res[wl][jj] = dres[0][wl][jj] + dres[1][wl][jj]
                    + ((jj < 12) ? b_delta[jj] : b_alpha[jj - 12]);
    }
    __syncthreads();

    // ---- per-point records into LDS (Prec overlays WcT storage) ----
    if (t < 32) {
        int wl = t >> 2, mm = t & 3;
        float l0 = res[wl][12], l1 = res[wl][13], l2 = res[wl][14], l3 = res[wl][15];
        float mx = fmaxf(fmaxf(l0, l1), fmaxf(l2, l3));
        float inv = 1.f / (expf(l0 - mx) + expf(l1 - mx) + expf(l2 - mx) + expf(l3 - mx));
        // -lam_sp*|dsec| shift is constant across M -> drops out of softmax
        float wgt = expf(res[wl][12 + mm] - mx) * inv;

        float cx = fminf(fmaxf(sref[0] + tanhf(res[wl][mm * 3 + 0]), 0.f), 1.f);
        float cy = fminf(fmaxf(sref[1] + tanhf(res[wl][mm * 3 + 1]), 0.f), 1.f);
        float tgt = (float)wl + tanhf(res[wl][mm * 3 + 2]);
        float t0f = fminf(fmaxf(floorf(tgt), 0.f), (float)(WL - 1));
        float t1f = fminf(t0f + 1.f, (float)(WL - 1));
        float alpha = tgt - t0f;
        float px = cx * (float)Ww - 0.5f, py = cy * (float)Hh - 0.5f;
        float fx = floorf(px), fy = floorf(py);
        float wx = px - fx, wy = py - fy;
        int X0 = (int)fminf(fmaxf(fx, 0.f), (float)(Ww - 1));
        int X1 = (int)fminf(fmaxf(fx + 1.f, 0.f), (float)(Ww - 1));
        int Y0 = (int)fminf(fmaxf(fy, 0.f), (float)(Hh - 1));
        int Y1 = (int)fminf(fmaxf(fy + 1.f, 0.f), (float)(Hh - 1));
        int T0 = (int)t0f, T1 = (int)t1f;

        float w00 = (1.f - wy) * (1.f - wx), w01 = (1.f - wy) * wx;
        float w10 = wy * (1.f - wx), w11 = wy * wx;
        float wt0 = wgt * (1.f - alpha), wt1 = wgt * alpha;

        int b = bq / Qn;
        int base0 = (b * WL + T0) * Hh;
        int base1 = (b * WL + T1) * Hh;
        int i00 = (base0 + Y0) * Ww + X0, i01 = (base0 + Y0) * Ww + X1;
        int i10 = (base0 + Y1) * Ww + X0, i11 = (base0 + Y1) * Ww + X1;
        int j00 = (base1 + Y0) * Ww + X0, j01 = (base1 + Y0) * Ww + X1;
        int j10 = (base1 + Y1) * Ww + X0, j11 = (base1 + Y1) * Ww + X1;

        unsigned* rec = &Prec[t * 16];
        rec[0] = __float_as_uint(wt0 * w00 * (mask[i00] ? 0.f : 1.f));
        rec[1] = __float_as_uint(wt0 * w01 * (mask[i01] ? 0.f : 1.f));
        rec[2] = __float_as_uint(wt0 * w10 * (mask[i10] ? 0.f : 1.f));
        rec[3] = __float_as_uint(wt0 * w11 * (mask[i11] ? 0.f : 1.f));
        rec[4] = __float_as_uint(wt1 * w00 * (mask[j00] ? 0.f : 1.f));
        rec[5] = __float_as_uint(wt1 * w01 * (mask[j01] ? 0.f : 1.f));
        rec[6] = __float_as_uint(wt1 * w10 * (mask[j10] ? 0.f : 1.f));
        rec[7] = __float_as_uint(wt1 * w11 * (mask[j11] ? 0.f : 1.f));
        rec[8] = i00; rec[9] = i01; rec[10] = i10; rec[11] = i11;
        rec[12] = j00; rec[13] = j01; rec[14] = j10; rec[15] = j11;
    }
    __syncthreads();

    // ---- gather + weighted aggregation (wave j owns points 4j..4j+3) ----
    {
        const float4* f4 = (const float4*)feats;
        int j = t >> 6;
        float4 acc = {0.f, 0.f, 0.f, 0.f};
#pragma unroll
        for (int p = 0; p < 4; p++) {
            const unsigned* rec = &Prec[(j * 4 + p) * 16];
#pragma unroll
            for (int cn = 0; cn < 8; cn++) {
                float w = __uint_as_float(rec[cn]);
                size_t idx = rec[8 + cn];
                float4 vv = f4[idx * 64 + lane];
                acc.x += w * vv.x; acc.y += w * vv.y; acc.z += w * vv.z; acc.w += w * vv.w;
            }
        }
        ((float4*)&part[j][0])[lane] = acc;
    }
    __syncthreads();
    if (t < 256) {
        agg[(size_t)bq * Dd + t] = part[0][t] + part[1][t] + part[2][t] + part[3][t]
                                 + part[4][t] + part[5][t] + part[6][t] + part[7][t];
    }
}

// ---------------- kernel 2: proj + residual + LN2 + FFN (+residual) ----------------
// 256 blocks x 1024 threads, 1 block/CU. Activations staged as packed f16x2 in LDS;
// inner loops use v_dot2_f32_f16 (fp32 accumulate): per group per column
// 1 LDS b128 + 4 dot2 replaces 2 b128 + 8 unpack + 8 fma -> ~3x fewer issue slots.
template<int R>
__device__ __forceinline__ void out_body(int row0,
        const float* __restrict__ q, const float* __restrict__ agg,
        const unsigned* __restrict__ pkP, const float* __restrict__ b_proj,
        const float* __restrict__ g2, const float* __restrict__ b2,
        const unsigned* __restrict__ pkF1, const float* __restrict__ b_ffn1,
        const unsigned* __restrict__ pkF2, const float* __restrict__ b_ffn2,
        float* __restrict__ out,
        unsigned* sA2, float* sO, unsigned* sH2, unsigned* sF2, float* sX, float* sRed) {
    int t = threadIdx.x;
    int j8 = t >> 7, c7 = t & 127;

    // ---- stage agg as f16x2 pairs ----
    for (int u = t; u < 128 * R; u += 1024) {
        int r = u >> 7, c2 = u & 127;
        float2 av = *(const float2*)&agg[(size_t)(row0 + r) * Dd + 2 * c2];
        sA2[r * 128 + c2] = packh2(av.x, av.y);
    }
    __syncthreads();

    // ---- proj: K-eighth j8 (4 groups), cols {c7, c7+128} ----
    {
        float a0[R], a1[R];
#pragma unroll
        for (int r = 0; r < R; r++) { a0[r] = 0.f; a1[r] = 0.f; }
#pragma unroll
        for (int gg = 0; gg < 4; gg++) {
            int g = j8 * 4 + gg;
            uint4 wv0 = *(const uint4*)&pkP[((unsigned)(g * 256 + c7)) * 4];
            uint4 wv1 = *(const uint4*)&pkP[((unsigned)(g * 256 + c7 + 128)) * 4];
#pragma unroll
            for (int r = 0; r < R; r++) {
                uint4 av = ((const uint4*)&sA2[r * 128])[g];
                a0[r] = dot8h(av, wv0, a0[r]);
                a1[r] = dot8h(av, wv1, a1[r]);
            }
        }
#pragma unroll
        for (int r = 0; r < R; r++) {
            sX[(j8 * R + r) * 256 + c7] = a0[r];
            sX[(j8 * R + r) * 256 + c7 + 128] = a1[r];
        }
    }
    __syncthreads();

    // ---- combine + residual (fp32) ----
    for (int u = t; u < 256 * R; u += 1024) {
        int r = u >> 8, cc = u & 255;
        float o = q[(size_t)(row0 + r) * Dd + cc] + b_proj[cc];
#pragma unroll
        for (int jj = 0; jj < 8; jj++) o += sX[(jj * R + r) * 256 + cc];
        sO[r * 256 + cc] = o;
    }
    __syncthreads();

    // ---- LN2: wave r reduces row r ----
    {
        int wv = t >> 6, l = t & 63;
        if (wv < R) {
            float4 vv = ((const float4*)&sO[wv * 256])[l];
            float s = vv.x + vv.y + vv.z + vv.w;
            s = __shfl(wave_reduce(s), 0, 64);
            float mean = s * (1.f / 256.f);
            float d0 = vv.x - mean, d1 = vv.y - mean, d2 = vv.z - mean, d3 = vv.w - mean;
            float ss = d0 * d0 + d1 * d1 + d2 * d2 + d3 * d3;
            ss = __shfl(wave_reduce(ss), 0, 64);
            float rstd = rsqrtf(ss * (1.f / 256.f) + 1e-5f);
            if (l == 0) { sRed[wv * 2] = mean; sRed[wv * 2 + 1] = rstd; }
        }
    }
    __syncthreads();
    for (int u = t; u < 128 * R; u += 1024) {
        int r = u >> 7, c2 = u & 127;
        int cc = 2 * c2;
        float mean = sRed[r * 2], rstd = sRed[r * 2 + 1];
        float h0 = (sO[r * 256 + cc] - mean) * rstd * g2[cc] + b2[cc];
        float h1 = (sO[r * 256 + cc + 1] - mean) * rstd * g2[cc + 1] + b2[cc + 1];
        sH2[r * 128 + c2] = packh2(h0, h1);
    }
    __syncthreads();

    // ---- FFN1: K-half h (16 groups), cols {c2c, c2c+512}, fp32 partials to sX ----
    {
        int h = t >> 9, c2c = t & 511;
        float f0[R], f1[R];
#pragma unroll
        for (int r = 0; r < R; r++) { f0[r] = 0.f; f1[r] = 0.f; }
#pragma unroll 2
        for (int gg = 0; gg < 16; gg++) {
            int g = h * 16 + gg;
            uint4 wv0 = *(const uint4*)&pkF1[((unsigned)(g * 1024 + c2c)) * 4];
            uint4 wv1 = *(const uint4*)&pkF1[((unsigned)(g * 1024 + c2c + 512)) * 4];
#pragma unroll
            for (int r = 0; r < R; r++) {
                uint4 av = ((const uint4*)&sH2[r * 128])[g];
                f0[r] = dot8h(av, wv0, f0[r]);
                f1[r] = dot8h(av, wv1, f1[r]);
            }
        }
        float* dst = sX + h * (R * 1024);
#pragma unroll
        for (int r = 0; r < R; r++) {
            dst[r * 1024 + c2c] = f0[r];
            dst[r * 1024 + c2c + 512] = f1[r];
        }
    }
    __syncthreads();

    // ---- combine K-halves + bias + exact GELU, pack to f16x2 ----
    for (int u = t; u < 512 * R; u += 1024) {
        int r = u >> 9, p = u & 511;
        float2 pa = ((const float2*)&sX[r * 1024])[p];
        float2 pb = ((const float2*)&sX[R * 1024 + r * 1024])[p];
        float2 bf = *(const float2*)&b_ffn1[2 * p];
        float x0 = pa.x + pb.x + bf.x;
        float x1 = pa.y + pb.y + bf.y;
        float e0 = 0.5f * x0 * (1.f + erff(x0 * 0.70710678118654752f));
        float e1 = 0.5f * x1 * (1.f + erff(x1 * 0.70710678118654752f));
        sF2[r * 512 + p] = packh2(e0, e1);
    }
    __syncthreads();

    // ---- FFN2: K-eighth j8 (16 groups), cols {c7, c7+128} ----
    {
        float a0[R], a1[R];
#pragma unroll
        for (int r = 0; r < R; r++) { a0[r] = 0.f; a1[r] = 0.f; }
#pragma unroll 2
        for (int gg = 0; gg < 16; gg++) {
            int g = j8 * 16 + gg;
            uint4 wv0 = *(const uint4*)&pkF2[((unsigned)(g * 256 + c7)) * 4];
            uint4 wv1 = *(const uint4*)&pkF2[((unsigned)(g * 256 + c7 + 128)) * 4];
#pragma unroll
            for (int r = 0; r < R; r++) {
                uint4 av = ((const uint4*)&sF2[r * 512])[g];
                a0[r] = dot8h(av, wv0, a0[r]);
                a1[r] = dot8h(av, wv1, a1[r]);
            }
        }
#pragma unroll
        for (int r = 0; r < R; r++) {
            sX[(j8 * R + r) * 256 + c7] = a0[r];
            sX[(j8 * R + r) * 256 + c7 + 128] = a1[r];
        }
    }
    __syncthreads();

    for (int u = t; u < 256 * R; u += 1024) {
        int r = u >> 8, cc = u & 255;
        float s = b_ffn2[cc];
#pragma unroll
        for (int jj = 0; jj < 8; jj++) s += sX[(jj * R + r) * 256 + cc];
        out[(size_t)(row0 + r) * Dd + cc] = sO[r * 256 + cc] + s;
    }
}

__global__ void __launch_bounds__(1024) k_out(const float* __restrict__ q,
                                              const float* __restrict__ agg,
                                              const unsigned* __restrict__ pkP,
                                              const float* __restrict__ b_proj,
                                              const float* __restrict__ g2,
                                              const float* __restrict__ b2,
                                              const unsigned* __restrict__ pkF1,
                                              const float* __restrict__ b_ffn1,
                                              const unsigned* __restrict__ pkF2,
                                              const float* __restrict__ b_ffn2,
                                              float* __restrict__ out) {
    __shared__ __align__(16) unsigned sA2[5 * 128];
    __shared__ __align__(16) float sO[5 * 256];
    __shared__ __align__(16) unsigned sH2[5 * 128];
    __shared__ __align__(16) unsigned sF2[5 * 512];
    __shared__ __align__(16) float sX[10240];   // fp32 partials: proj/FFN2 8x, FFN1 2x
    __shared__ float sRed[16];
    __shared__ float pad[5120];   // inflate LDS past 80KB -> exactly 1 block/CU
    if (b_ffn2 == nullptr) pad[threadIdx.x & 1023] = 0.f;   // keeps pad alive; never executes

    int bid = blockIdx.x;
    if (bid < 176) {
        out_body<5>(bid * 5, q, agg, pkP, b_proj, g2, b2, pkF1, b_ffn1, pkF2, b_ffn2,
                    out, sA2, sO, sH2, sF2, sX, sRed);
    } else {
        out_body<4>(880 + (bid - 176) * 4, q, agg, pkP, b_proj, g2, b2, pkF1, b_ffn1,
                    pkF2, b_ffn2, out, sA2, sO, sH2, sF2, sX, sRed);
    }
}

// ---------------- launcher ----------------
extern "C" void kernel_launch(void* const* d_in, const int* in_sizes, int n_in,
                              void* d_out, int out_size, void* d_ws, size_t ws_size,
                              hipStream_t stream) {
    const float* q        = (const float*)d_in[0];
    const float* kv_feats = (const float*)d_in[1];
    const unsigned char* kv_mask = (const unsigned char*)d_in[2];
    const float* delta_sec= (const float*)d_in[3];
    const float* w_ref    = (const float*)d_in[4];
    const float* b_ref    = (const float*)d_in[5];
    const float* w_delta  = (const float*)d_in[6];
    const float* b_delta  = (const float*)d_in[7];
    const float* w_alpha  = (const float*)d_in[8];
    const float* b_alpha  = (const float*)d_in[9];
    // d_in[10] = lam: softmax shift-invariance makes it a no-op
    const float* w_proj   = (const float*)d_in[11];
    const float* b_proj   = (const float*)d_in[12];
    const float* ln1_g    = (const float*)d_in[13];
    const float* ln1_b    = (const float*)d_in[14];
    const float* ln2_g    = (const float*)d_in[15];
    const float* ln2_b    = (const float*)d_in[16];
    const float* w_ffn1   = (const float*)d_in[17];
    const float* b_ffn1   = (const float*)d_in[18];
    const float* w_ffn2   = (const float*)d_in[19];
    const float* b_ffn2   = (const float*)d_in[20];
    const float* w_rel    = (const float*)d_in[21];
    const float* b_rel    = (const float*)d_in[22];
    float* out = (float*)d_out;

    unsigned* pk   = (unsigned*)d_ws;                  // 294912 uints
    unsigned* pkP  = pk;
    unsigned* pkF1 = pk + 32768;
    unsigned* pkF2 = pk + 163840;
    float*    agg  = (float*)(pk + 294912);            // 307200 floats

    const int BQ = Bn * Qn;                            // 1200
    k_front<<<dim3(576 + BQ), dim3(512), 0, stream>>>(w_proj, w_ffn1, w_ffn2, pk,
                                                      q, ln1_g, ln1_b, w_ref, b_ref,
                                                      delta_sec, w_rel, b_rel,
                                                      w_delta, b_delta, w_alpha, b_alpha,
                                                      kv_mask, kv_feats, agg);
    k_out<<<dim3(256), dim3(1024), 0, stream>>>(q, agg, pkP, b_proj, ln2_g, ln2_b,
                                                pkF1, b_ffn1, pkF2, b_ffn2, out);
}